// Round 1
// baseline (271.379 us; speedup 1.0000x reference)
//
#include <hip/hip_runtime.h>

#define EMBED 1024
#define HEADS 16
#define HDIM 64
#define SQ 1023        // word sequence length
#define SK 1024        // keys = 1 image + 1023 word; also padded Q rows
#define MTOK 4092      // 4*1023 valid token rows
#define MPAD 4096      // padded to 128 multiple

typedef __attribute__((ext_vector_type(8))) short short8;
typedef __attribute__((ext_vector_type(4))) float floatx4;

static __device__ __forceinline__ unsigned short f2bf(float f) {
  union { float f; unsigned u; } v; v.f = f;
  unsigned u = v.u;
  u += 0x7fffu + ((u >> 16) & 1u);
  return (unsigned short)(u >> 16);
}

// ---------------- prep kernels ----------------

// word (4092x1024 f32) -> A bf16 padded to 4096 rows (pad rows = 0)
__global__ __launch_bounds__(256) void k_cast_word(const float* __restrict__ W,
                                                   unsigned short* __restrict__ A) {
  int idx = (blockIdx.x * 256 + threadIdx.x) * 8;
  int row = idx >> 10;
  short8 v;
  if (row < MTOK) {
    const float4* p = (const float4*)(W + idx);
    float4 a = p[0], b = p[1];
    v[0] = (short)f2bf(a.x); v[1] = (short)f2bf(a.y);
    v[2] = (short)f2bf(a.z); v[3] = (short)f2bf(a.w);
    v[4] = (short)f2bf(b.x); v[5] = (short)f2bf(b.y);
    v[6] = (short)f2bf(b.z); v[7] = (short)f2bf(b.w);
  } else {
#pragma unroll
    for (int i = 0; i < 8; i++) v[i] = 0;
  }
  *(short8*)(A + idx) = v;
}

// W (K x N f32 row-major) -> Wt (N x K bf16 row-major)
__global__ __launch_bounds__(256) void k_transpose_cast(const float* __restrict__ W,
                                                        unsigned short* __restrict__ Wt,
                                                        int K, int N) {
  __shared__ float T[32][33];
  int tx = threadIdx.x & 31, ty = threadIdx.x >> 5;
  int n0 = blockIdx.x * 32, k0 = blockIdx.y * 32;
#pragma unroll
  for (int i = 0; i < 4; i++) {
    int r = ty + i * 8;
    T[r][tx] = W[(k0 + r) * N + n0 + tx];
  }
  __syncthreads();
#pragma unroll
  for (int i = 0; i < 4; i++) {
    int r = ty + i * 8;
    Wt[(n0 + r) * K + k0 + tx] = f2bf(T[tx][r]);
  }
}

// image K/V rows: k_img[b][n] = sum_k img[b][k]*uk_w[n][k] + uk_b[n] -> key row 0
__global__ __launch_bounds__(256) void k_img_kv(const float* __restrict__ img,
    const float* __restrict__ ukw, const float* __restrict__ ukb,
    const float* __restrict__ uvw, const float* __restrict__ uvb,
    unsigned short* __restrict__ Kb, unsigned short* __restrict__ Vb) {
  int wid = blockIdx.x * 4 + (threadIdx.x >> 6);
  int lane = threadIdx.x & 63;
  int which = wid >> 12;            // 0: k, 1: v
  int bb = (wid >> 10) & 3;
  int n = wid & 1023;
  const float* W = which ? uvw : ukw;
  const float* bias = which ? uvb : ukb;
  unsigned short* out = which ? Vb : Kb;
  const float* x = img + bb * 1024;
  const float* w = W + n * 1024;
  float s = 0.f;
#pragma unroll
  for (int i = 0; i < 16; i++) { int k = i * 64 + lane; s += x[k] * w[k]; }
#pragma unroll
  for (int off = 32; off; off >>= 1) s += __shfl_xor(s, off);
  if (lane == 0) {
    int h = n >> 6, d = n & 63;
    out[((bb * HEADS + h) * SK + 0) * HDIM + d] = f2bf(s + bias[n]);
  }
}

// zero Q pad row (s = 1023) so flash's last tile reads clean data
__global__ void k_zero_qpad(unsigned short* __restrict__ Qb) {
  int i = blockIdx.x * 256 + threadIdx.x;   // 4096 = 4*16*64
  int bh = i >> 6, d = i & 63;
  Qb[(bh * SK + (SK - 1)) * HDIM + d] = 0;
}

// ---------------- MFMA GEMM: C[m][n] = sum_k A[m][k]*Bt[n][k] (+bias) ----------------
// 128x128 tile, 4 waves of 64x64, BK=32, 16x16x32 bf16 MFMA.
// EPI 0: scatter qkv into head-split Q/K/V bf16.  EPI 1: f32 store to out.
template <int EPI>
__global__ __launch_bounds__(256, 2) void k_gemm(
    const unsigned short* __restrict__ A, const unsigned short* __restrict__ Bt,
    int Kdim, const float* __restrict__ bias,
    unsigned short* __restrict__ Qb, unsigned short* __restrict__ Kb,
    unsigned short* __restrict__ Vb, float* __restrict__ out) {
  __shared__ unsigned short As[128 * 40];   // row stride 40 ushorts (80B): 2-way banks
  __shared__ unsigned short Bs[128 * 40];
  int t = threadIdx.x;
  int lane = t & 63, w = t >> 6;
  int quad = lane >> 4, l16 = lane & 15;
  int m0 = blockIdx.y * 128, n0 = blockIdx.x * 128;
  int waveM = (w >> 1) * 64, waveN = (w & 1) * 64;

  floatx4 acc[4][4];
#pragma unroll
  for (int i = 0; i < 4; i++)
#pragma unroll
    for (int j = 0; j < 4; j++)
#pragma unroll
      for (int e = 0; e < 4; e++) acc[i][j][e] = 0.f;

  int r0 = t >> 2, c0 = t & 3;            // chunk 0: rows 0..63
  int r1 = 64 + r0, c1 = c0;              // chunk 1: rows 64..127
  const unsigned short* Ag = A + m0 * Kdim;
  const unsigned short* Bg = Bt + n0 * Kdim;

  for (int k0 = 0; k0 < Kdim; k0 += 32) {
    short8 a0 = *(const short8*)(Ag + r0 * Kdim + k0 + c0 * 8);
    short8 a1 = *(const short8*)(Ag + r1 * Kdim + k0 + c1 * 8);
    short8 b0 = *(const short8*)(Bg + r0 * Kdim + k0 + c0 * 8);
    short8 b1 = *(const short8*)(Bg + r1 * Kdim + k0 + c1 * 8);
    __syncthreads();
    *(short8*)(As + r0 * 40 + c0 * 8) = a0;
    *(short8*)(As + r1 * 40 + c1 * 8) = a1;
    *(short8*)(Bs + r0 * 40 + c0 * 8) = b0;
    *(short8*)(Bs + r1 * 40 + c1 * 8) = b1;
    __syncthreads();
    short8 af[4], bfr[4];
#pragma unroll
    for (int mr = 0; mr < 4; mr++) {
      int row = waveM + mr * 16 + l16;
      af[mr] = *(const short8*)(As + row * 40 + quad * 8);
    }
#pragma unroll
    for (int nc = 0; nc < 4; nc++) {
      int row = waveN + nc * 16 + l16;
      bfr[nc] = *(const short8*)(Bs + row * 40 + quad * 8);
    }
#pragma unroll
    for (int mr = 0; mr < 4; mr++)
#pragma unroll
      for (int nc = 0; nc < 4; nc++)
        acc[mr][nc] = __builtin_amdgcn_mfma_f32_16x16x32_bf16(af[mr], bfr[nc], acc[mr][nc], 0, 0, 0);
  }

  // epilogue: C/D layout col=l16, row=quad*4+reg  [measured m89/m91]
  if (EPI == 0) {
#pragma unroll
    for (int nc = 0; nc < 4; nc++) {
      int gn = n0 + waveN + nc * 16 + l16;
      float bv = bias[gn];
      int which = gn >> 10;               // 0:q 1:k 2:v (uniform per nc tile)
      int e = gn & 1023;
      int h = e >> 6, d = e & 63;
      unsigned short* dst = (which == 0) ? Qb : (which == 1) ? Kb : Vb;
      int sofs = (which == 0) ? 0 : 1;    // image occupies key row 0
#pragma unroll
      for (int mr = 0; mr < 4; mr++) {
        floatx4 c = acc[mr][nc];
#pragma unroll
        for (int r = 0; r < 4; r++) {
          int gm = m0 + waveM + mr * 16 + quad * 4 + r;
          if (gm < MTOK) {
            int bb = (unsigned)gm / 1023u;
            int s = gm - bb * 1023;
            dst[((bb * HEADS + h) * SK + s + sofs) * HDIM + d] = f2bf(c[r] + bv);
          }
        }
      }
    }
  } else {
#pragma unroll
    for (int nc = 0; nc < 4; nc++) {
      int gn = n0 + waveN + nc * 16 + l16;
      float bv = bias[gn];
#pragma unroll
      for (int mr = 0; mr < 4; mr++) {
        floatx4 c = acc[mr][nc];
#pragma unroll
        for (int r = 0; r < 4; r++) {
          int gm = m0 + waveM + mr * 16 + quad * 4 + r;
          if (gm < MTOK) out[gm * EMBED + gn] = c[r] + bv;
        }
      }
    }
  }
}

// ---------------- flash attention ----------------
// grid: x = 16 Q-tiles of 64 rows, y = 64 (b*16+h). 4 waves, 16 q-rows/wave.
__global__ __launch_bounds__(256, 2) void k_flash(
    const unsigned short* __restrict__ Qb, const unsigned short* __restrict__ Kb,
    const unsigned short* __restrict__ Vb, const float* __restrict__ am,
    unsigned short* __restrict__ Ao) {
  __shared__ unsigned short Qs[64 * 72];     // stride 72
  __shared__ unsigned short Ks[128 * 72];
  __shared__ unsigned short Vt[64 * 136];    // transposed: Vt[d][key], stride 136
  __shared__ unsigned short Ps[4][16 * 136]; // per-wave P in A-layout staging

  int t = threadIdx.x, lane = t & 63, w = t >> 6;
  int quad = lane >> 4, l16 = lane & 15;
  int tq = blockIdx.x;
  int bh = blockIdx.y;
  int bb = bh >> 4, h = bh & 15;

  const unsigned short* Qg = Qb + (bh * SK + tq * 64) * HDIM;
  const unsigned short* Kg = Kb + bh * SK * HDIM;
  const unsigned short* Vg = Vb + bh * SK * HDIM;

  // stage Q once
#pragma unroll
  for (int i = 0; i < 2; i++) {
    int c = i * 256 + t, r = c >> 3, cg = c & 7;
    short8 v = *(const short8*)(Qg + r * 64 + cg * 8);
    *(short8*)(Qs + r * 72 + cg * 8) = v;
  }

  float m_i[4], l_i[4];
  floatx4 acc_o[4];
#pragma unroll
  for (int r = 0; r < 4; r++) { m_i[r] = -1e30f; l_i[r] = 0.f; }
#pragma unroll
  for (int n = 0; n < 4; n++)
#pragma unroll
    for (int e = 0; e < 4; e++) acc_o[n][e] = 0.f;

  int jmax = min((tq + 1) >> 1, 7);
  for (int j = 0; j <= jmax; j++) {
    __syncthreads();   // protect Ks/Vt from previous iter's readers (and Qs stage 1st iter)
#pragma unroll
    for (int i = 0; i < 4; i++) {
      int c = i * 256 + t, r = c >> 3, cg = c & 7;
      short8 v = *(const short8*)(Kg + (j * 128 + r) * 64 + cg * 8);
      *(short8*)(Ks + r * 72 + cg * 8) = v;
    }
#pragma unroll
    for (int i = 0; i < 4; i++) {
      int c = i * 256 + t, r = c >> 3, cg = c & 7;   // r = key
      short8 v = *(const short8*)(Vg + (j * 128 + r) * 64 + cg * 8);
#pragma unroll
      for (int e = 0; e < 8; e++) Vt[(cg * 8 + e) * 136 + r] = (unsigned short)v[e];
    }
    __syncthreads();

    // S = Q K^T : wave computes rows w*16..+15 x 128 cols
    floatx4 sacc[8];
#pragma unroll
    for (int n = 0; n < 8; n++)
#pragma unroll
      for (int e = 0; e < 4; e++) sacc[n][e] = 0.f;
#pragma unroll
    for (int kk = 0; kk < 2; kk++) {
      short8 a = *(const short8*)(Qs + (w * 16 + l16) * 72 + kk * 32 + quad * 8);
#pragma unroll
      for (int nc = 0; nc < 8; nc++) {
        short8 b = *(const short8*)(Ks + (nc * 16 + l16) * 72 + kk * 32 + quad * 8);
        sacc[nc] = __builtin_amdgcn_mfma_f32_16x16x32_bf16(a, b, sacc[nc], 0, 0, 0);
      }
    }

    // scale, causal mask (kj <= qi+1 else -10000), + attention_mask
    bool needmask = (j * 128 + 127 > tq * 64 + 1);
    int qbase = tq * 64 + w * 16 + quad * 4;
    float sval[8][4], tmax[4];
#pragma unroll
    for (int r = 0; r < 4; r++) tmax[r] = -1e30f;
#pragma unroll
    for (int nc = 0; nc < 8; nc++) {
      int kg = j * 128 + nc * 16 + l16;
      float amv = (kg >= 1) ? am[bb * SQ + kg - 1] : 0.f;
#pragma unroll
      for (int r = 0; r < 4; r++) {
        float sc = sacc[nc][r] * 0.125f;
        if (needmask && kg > qbase + r + 1) sc = -10000.0f;
        sc += amv;
        sval[nc][r] = sc;
        tmax[r] = fmaxf(tmax[r], sc);
      }
    }
#pragma unroll
    for (int off = 1; off < 16; off <<= 1)
#pragma unroll
      for (int r = 0; r < 4; r++) tmax[r] = fmaxf(tmax[r], __shfl_xor(tmax[r], off));

    float alpha[4];
#pragma unroll
    for (int r = 0; r < 4; r++) {
      float mn = fmaxf(m_i[r], tmax[r]);
      alpha[r] = __expf(m_i[r] - mn);
      m_i[r] = mn;
    }
    float rsum[4] = {0.f, 0.f, 0.f, 0.f};
#pragma unroll
    for (int nc = 0; nc < 8; nc++)
#pragma unroll
      for (int r = 0; r < 4; r++) {
        float p = __expf(sval[nc][r] - m_i[r]);
        sval[nc][r] = p;
        rsum[r] += p;
      }
#pragma unroll
    for (int off = 1; off < 16; off <<= 1)
#pragma unroll
      for (int r = 0; r < 4; r++) rsum[r] += __shfl_xor(rsum[r], off);
#pragma unroll
    for (int r = 0; r < 4; r++) l_i[r] = l_i[r] * alpha[r] + rsum[r];
#pragma unroll
    for (int n = 0; n < 4; n++)
#pragma unroll
      for (int e = 0; e < 4; e++) acc_o[n][e] *= alpha[e];

    // P: C-layout -> LDS -> A-layout (wave-private region)
    unsigned short* Pw = (unsigned short*)Ps[w];
#pragma unroll
    for (int nc = 0; nc < 8; nc++)
#pragma unroll
      for (int r = 0; r < 4; r++)
        Pw[(quad * 4 + r) * 136 + nc * 16 + l16] = f2bf(sval[nc][r]);
    __syncthreads();

    // O += P V
#pragma unroll
    for (int kk2 = 0; kk2 < 4; kk2++) {
      short8 a = *(const short8*)(Pw + l16 * 136 + kk2 * 32 + quad * 8);
#pragma unroll
      for (int n = 0; n < 4; n++) {
        short8 b = *(const short8*)(Vt + (n * 16 + l16) * 136 + kk2 * 32 + quad * 8);
        acc_o[n] = __builtin_amdgcn_mfma_f32_16x16x32_bf16(a, b, acc_o[n], 0, 0, 0);
      }
    }
  }

  // normalize + store into attn_out (A matrix for proj GEMM)
  float inv[4];
#pragma unroll
  for (int r = 0; r < 4; r++) inv[r] = 1.f / l_i[r];
#pragma unroll
  for (int n = 0; n < 4; n++)
#pragma unroll
    for (int r = 0; r < 4; r++) {
      int q = tq * 64 + w * 16 + quad * 4 + r;
      if (q < SQ) {
        float val = acc_o[n][r] * inv[r];
        Ao[(bb * SQ + q) * EMBED + h * HDIM + n * 16 + l16] = f2bf(val);
      }
    }
}

// ---------------- launch ----------------
extern "C" void kernel_launch(void* const* d_in, const int* in_sizes, int n_in,
                              void* d_out, int out_size, void* d_ws, size_t ws_size,
                              hipStream_t stream) {
  const float* word   = (const float*)d_in[0];
  const float* img    = (const float*)d_in[1];
  const float* amask  = (const float*)d_in[2];
  const float* attn_w = (const float*)d_in[3];
  const float* attn_b = (const float*)d_in[4];
  const float* proj_w = (const float*)d_in[5];
  const float* proj_b = (const float*)d_in[6];
  const float* ukw    = (const float*)d_in[7];
  const float* ukb    = (const float*)d_in[8];
  const float* uvw    = (const float*)d_in[9];
  const float* uvb    = (const float*)d_in[10];
  float* out = (float*)d_out;

  char* ws = (char*)d_ws;
  unsigned short* Aw     = (unsigned short*)(ws);                 // 4096x1024 bf16 (8 MB)
  unsigned short* WtAttn = (unsigned short*)(ws + 8388608);       // 3072x1024 bf16 (6 MB)
  unsigned short* WtProj = (unsigned short*)(ws + 14680064);      // 1024x1024 bf16 (2 MB)
  unsigned short* Qb     = (unsigned short*)(ws + 16777216);      // 4x16x1024x64 bf16 (8 MB)
  unsigned short* Kb     = (unsigned short*)(ws + 25165824);      // 8 MB
  unsigned short* Vb     = (unsigned short*)(ws + 33554432);      // 8 MB
  unsigned short* Ao     = Aw;  // reuse A region: A dead after QKV GEMM

  k_cast_word<<<2048, 256, 0, stream>>>(word, Aw);
  k_transpose_cast<<<dim3(96, 32), 256, 0, stream>>>(attn_w, WtAttn, 1024, 3072);
  k_transpose_cast<<<dim3(32, 32), 256, 0, stream>>>(proj_w, WtProj, 1024, 1024);
  k_img_kv<<<2048, 256, 0, stream>>>(img, ukw, ukb, uvw, uvb, Kb, Vb);
  k_zero_qpad<<<16, 256, 0, stream>>>(Qb);
  k_gemm<0><<<dim3(24, 32), 256, 0, stream>>>(Aw, WtAttn, 1024, attn_b, Qb, Kb, Vb, nullptr);
  k_flash<<<dim3(16, 64), 256, 0, stream>>>(Qb, Kb, Vb, amask, Ao);
  k_gemm<1><<<dim3(8, 32), 256, 0, stream>>>(Ao, WtProj, 1024, proj_b, nullptr, nullptr, nullptr, out);
}

// Round 2
// 239.995 us; speedup vs baseline: 1.1308x; 1.1308x over previous
//
#include <hip/hip_runtime.h>

#define EMBED 1024
#define HEADS 16
#define HDIM 64
#define SQ 1023        // word sequence length
#define SK 1024        // keys = 1 image + 1023 word; also padded Q rows
#define MTOK 4092      // 4*1023 valid token rows
#define MPAD 4096      // padded to 128 multiple

typedef __attribute__((ext_vector_type(8))) short short8;
typedef __attribute__((ext_vector_type(4))) float floatx4;

static __device__ __forceinline__ unsigned short f2bf(float f) {
  union { float f; unsigned u; } v; v.f = f;
  unsigned u = v.u;
  u += 0x7fffu + ((u >> 16) & 1u);
  return (unsigned short)(u >> 16);
}

// async global->LDS, 16B per lane. LDS dest = wave-uniform base + lane*16.
static __device__ __forceinline__ void gld16(const unsigned short* g, unsigned short* l) {
  typedef const __attribute__((address_space(1))) unsigned int guint;
  typedef __attribute__((address_space(3))) unsigned int luint;
  __builtin_amdgcn_global_load_lds((guint*)(const void*)g, (luint*)(void*)l, 16, 0, 0);
}

// ---------------- prep kernels ----------------

// word (4092x1024 f32) -> A bf16 padded to 4096 rows (pad rows = 0)
__global__ __launch_bounds__(256) void k_cast_word(const float* __restrict__ W,
                                                   unsigned short* __restrict__ A) {
  int idx = (blockIdx.x * 256 + threadIdx.x) * 8;
  int row = idx >> 10;
  short8 v;
  if (row < MTOK) {
    const float4* p = (const float4*)(W + idx);
    float4 a = p[0], b = p[1];
    v[0] = (short)f2bf(a.x); v[1] = (short)f2bf(a.y);
    v[2] = (short)f2bf(a.z); v[3] = (short)f2bf(a.w);
    v[4] = (short)f2bf(b.x); v[5] = (short)f2bf(b.y);
    v[6] = (short)f2bf(b.z); v[7] = (short)f2bf(b.w);
  } else {
#pragma unroll
    for (int i = 0; i < 8; i++) v[i] = 0;
  }
  *(short8*)(A + idx) = v;
}

// W (K x N f32 row-major) -> Wt (N x K bf16 row-major)
__global__ __launch_bounds__(256) void k_transpose_cast(const float* __restrict__ W,
                                                        unsigned short* __restrict__ Wt,
                                                        int K, int N) {
  __shared__ float T[32][33];
  int tx = threadIdx.x & 31, ty = threadIdx.x >> 5;
  int n0 = blockIdx.x * 32, k0 = blockIdx.y * 32;
#pragma unroll
  for (int i = 0; i < 4; i++) {
    int r = ty + i * 8;
    T[r][tx] = W[(k0 + r) * N + n0 + tx];
  }
  __syncthreads();
#pragma unroll
  for (int i = 0; i < 4; i++) {
    int r = ty + i * 8;
    Wt[(n0 + r) * K + k0 + tx] = f2bf(T[tx][r]);
  }
}

// image K/V rows -> key/value row 0 of each (b,h)
__global__ __launch_bounds__(256) void k_img_kv(const float* __restrict__ img,
    const float* __restrict__ ukw, const float* __restrict__ ukb,
    const float* __restrict__ uvw, const float* __restrict__ uvb,
    unsigned short* __restrict__ Kb, unsigned short* __restrict__ Vb) {
  int wid = blockIdx.x * 4 + (threadIdx.x >> 6);
  int lane = threadIdx.x & 63;
  int which = wid >> 12;            // 0: k, 1: v
  int bb = (wid >> 10) & 3;
  int n = wid & 1023;
  const float* W = which ? uvw : ukw;
  const float* bias = which ? uvb : ukb;
  unsigned short* out = which ? Vb : Kb;
  const float* x = img + bb * 1024;
  const float* w = W + n * 1024;
  float s = 0.f;
#pragma unroll
  for (int i = 0; i < 16; i++) { int k = i * 64 + lane; s += x[k] * w[k]; }
#pragma unroll
  for (int off = 32; off; off >>= 1) s += __shfl_xor(s, off);
  if (lane == 0) {
    int h = n >> 6, d = n & 63;
    out[((bb * HEADS + h) * SK + 0) * HDIM + d] = f2bf(s + bias[n]);
  }
}

// zero Q pad row (s = 1023)
__global__ void k_zero_qpad(unsigned short* __restrict__ Qb) {
  int i = blockIdx.x * 256 + threadIdx.x;   // 4096 = 4*16*64
  int bh = i >> 6, d = i & 63;
  Qb[(bh * SK + (SK - 1)) * HDIM + d] = 0;
}

// V (bh,s,d) -> Vt (bh,d,s): 64x64 LDS tiles, coalesced both ways
__global__ __launch_bounds__(256) void k_vt(const unsigned short* __restrict__ V,
                                            unsigned short* __restrict__ Vt) {
  __shared__ unsigned short T[64 * 72];
  int t = threadIdx.x;
  int sb = blockIdx.x, bh = blockIdx.y;
  const unsigned short* src = V + (bh * SK + sb * 64) * HDIM;
#pragma unroll
  for (int i = 0; i < 2; i++) {
    int r = i * 32 + (t >> 3), c8 = t & 7;
    short8 v = *(const short8*)(src + r * 64 + c8 * 8);
    *(short8*)(T + r * 72 + c8 * 8) = v;
  }
  __syncthreads();
#pragma unroll
  for (int i = 0; i < 2; i++) {
    int cid = i * 256 + t;
    int d = cid >> 3, s8 = cid & 7;
    short8 v;
#pragma unroll
    for (int e = 0; e < 8; e++) v[e] = (short)T[(s8 * 8 + e) * 72 + d];
    *(short8*)(Vt + (bh * 64 + d) * SK + sb * 64 + s8 * 8) = v;
  }
}

// ---------------- MFMA GEMM: C[m][n] = sum_k A[m][k]*Bt[n][k] (+bias) ----------------
// 128x128 tile, 4 waves of 64x64, BK=64, global_load_lds 16B staging,
// unpadded LDS with XOR chunk swizzle (chunk ^= row&7).
template <int EPI>
__global__ __launch_bounds__(256, 2) void k_gemm(
    const unsigned short* __restrict__ A, const unsigned short* __restrict__ Bt,
    int Kdim, const float* __restrict__ bias,
    unsigned short* __restrict__ Qb, unsigned short* __restrict__ Kb,
    unsigned short* __restrict__ Vb, float* __restrict__ out) {
  __shared__ __attribute__((aligned(16))) unsigned short Sm[16384];  // As | Bs (32KB)
  unsigned short* As = Sm;           // [128][64], swizzled
  unsigned short* Bs = Sm + 8192;
  int t = threadIdx.x, lane = t & 63, w = t >> 6;
  int quad = lane >> 4, l16 = lane & 15;
  int m0 = blockIdx.y * 128, n0 = blockIdx.x * 128;
  int waveM = (w >> 1) * 64, waveN = (w & 1) * 64;
  int rs = t >> 3, cs = t & 7;

  floatx4 acc[4][4];
#pragma unroll
  for (int i = 0; i < 4; i++)
#pragma unroll
    for (int j = 0; j < 4; j++)
#pragma unroll
      for (int e = 0; e < 4; e++) acc[i][j][e] = 0.f;

  const unsigned short* Ag = A + m0 * Kdim;
  const unsigned short* Bg = Bt + n0 * Kdim;

  for (int k0 = 0; k0 < Kdim; k0 += 64) {
    __syncthreads();
#pragma unroll
    for (int i = 0; i < 4; i++) {
      int r = i * 32 + rs;
      gld16(Ag + r * Kdim + k0 + ((cs ^ (r & 7)) * 8), As + i * 2048 + t * 8);
    }
#pragma unroll
    for (int i = 0; i < 4; i++) {
      int r = i * 32 + rs;
      gld16(Bg + r * Kdim + k0 + ((cs ^ (r & 7)) * 8), Bs + i * 2048 + t * 8);
    }
    __syncthreads();
    short8 af[2][4], bf8[2][4];
#pragma unroll
    for (int kk = 0; kk < 2; kk++) {
#pragma unroll
      for (int mr = 0; mr < 4; mr++) {
        int row = waveM + mr * 16 + l16;
        af[kk][mr] = *(const short8*)(As + row * 64 + (((kk * 4 + quad) ^ (row & 7)) * 8));
      }
#pragma unroll
      for (int nc = 0; nc < 4; nc++) {
        int row = waveN + nc * 16 + l16;
        bf8[kk][nc] = *(const short8*)(Bs + row * 64 + (((kk * 4 + quad) ^ (row & 7)) * 8));
      }
    }
#pragma unroll
    for (int kk = 0; kk < 2; kk++)
#pragma unroll
      for (int mr = 0; mr < 4; mr++)
#pragma unroll
        for (int nc = 0; nc < 4; nc++)
          acc[mr][nc] = __builtin_amdgcn_mfma_f32_16x16x32_bf16(af[kk][mr], bf8[kk][nc], acc[mr][nc], 0, 0, 0);
  }

  float bv[4];
#pragma unroll
  for (int nc = 0; nc < 4; nc++) bv[nc] = bias[n0 + waveN + nc * 16 + l16];

  if (EPI == 0) {
    // repack through LDS (two 64-row passes), then vectorized head-split scatter
    unsigned short* Cs = Sm;         // [64][128] swizzled
    for (int p = 0; p < 2; p++) {
      __syncthreads();
      if ((w >> 1) == p) {
#pragma unroll
        for (int mr = 0; mr < 4; mr++)
#pragma unroll
          for (int nc = 0; nc < 4; nc++)
#pragma unroll
            for (int r = 0; r < 4; r++) {
              int lrow = mr * 16 + quad * 4 + r;
              int lcol = waveN + nc * 16 + l16;
              Cs[lrow * 128 + (((lcol >> 3) ^ (lrow & 7)) * 8) + (lcol & 7)] =
                  f2bf(acc[mr][nc][r] + bv[nc]);
            }
      }
      __syncthreads();
#pragma unroll
      for (int i = 0; i < 4; i++) {
        int cid = i * 256 + t;
        int lr = cid >> 4, c8 = cid & 15;
        short8 v = *(const short8*)(Cs + lr * 128 + ((c8 ^ (lr & 7)) * 8));
        int gm = m0 + p * 64 + lr;
        if (gm < MTOK) {
          int gn = n0 + c8 * 8;
          int which = gn >> 10, e = gn & 1023;
          int h = e >> 6, d0 = e & 63;
          unsigned short* dst = (which == 0) ? Qb : (which == 1) ? Kb : Vb;
          int sofs = (which == 0) ? 0 : 1;   // image occupies key/value row 0
          int bb = (unsigned)gm / 1023u;
          int s = gm - bb * 1023;
          *(short8*)(dst + ((bb * HEADS + h) * SK + s + sofs) * HDIM + d0) = v;
        }
      }
    }
  } else {
#pragma unroll
    for (int nc = 0; nc < 4; nc++) {
      int gn = n0 + waveN + nc * 16 + l16;
#pragma unroll
      for (int mr = 0; mr < 4; mr++) {
#pragma unroll
        for (int r = 0; r < 4; r++) {
          int gm = m0 + waveM + mr * 16 + quad * 4 + r;
          if (gm < MTOK) out[gm * EMBED + gn] = acc[mr][nc][r] + bv[nc];
        }
      }
    }
  }
}

// ---------------- flash attention ----------------
// grid: x = 16 Q-tiles of 64 rows, y = 64 (b*16+h). 4 waves, 16 q-rows/wave.
__global__ __launch_bounds__(256, 2) void k_flash(
    const unsigned short* __restrict__ Qb, const unsigned short* __restrict__ Kb,
    const unsigned short* __restrict__ Vtg, const float* __restrict__ am,
    unsigned short* __restrict__ Ao) {
  __shared__ __attribute__((aligned(16))) unsigned short Qs[4096];   // [64][64] swz
  __shared__ __attribute__((aligned(16))) unsigned short Ks[8192];   // [128][64] swz
  __shared__ __attribute__((aligned(16))) unsigned short Vs[8192];   // [64 d][128 s] swz
  __shared__ __attribute__((aligned(16))) unsigned short Ps[4 * 2304]; // per-wave P, stride 144

  int t = threadIdx.x, lane = t & 63, w = t >> 6;
  int quad = lane >> 4, l16 = lane & 15;
  int tq = blockIdx.x, bh = blockIdx.y;
  int bb = bh >> 4, h = bh & 15;

  // stage Q once (async; first in-loop barrier drains it)
#pragma unroll
  for (int i = 0; i < 2; i++) {
    int r = i * 32 + (t >> 3), gc = (t & 7) ^ (r & 7);
    gld16(Qb + (bh * SK + tq * 64 + r) * HDIM + gc * 8, Qs + i * 2048 + t * 8);
  }

  float m_i[4], l_i[4];
  floatx4 acc_o[4];
#pragma unroll
  for (int r = 0; r < 4; r++) { m_i[r] = -1e30f; l_i[r] = 0.f; }
#pragma unroll
  for (int n = 0; n < 4; n++)
#pragma unroll
    for (int e = 0; e < 4; e++) acc_o[n][e] = 0.f;

  unsigned short* Pw = Ps + w * 2304;
  int jmax = min((tq + 1) >> 1, 7);
  for (int j = 0; j <= jmax; j++) {
    __syncthreads();   // prior readers done; also drains pending GLDs
#pragma unroll
    for (int i = 0; i < 4; i++) {
      int r = i * 32 + (t >> 3), gc = (t & 7) ^ (r & 7);
      gld16(Kb + (bh * SK + j * 128 + r) * HDIM + gc * 8, Ks + i * 2048 + t * 8);
    }
#pragma unroll
    for (int i = 0; i < 4; i++) {
      int d = i * 16 + (t >> 4), gc = (t & 15) ^ (d & 7);
      gld16(Vtg + (bh * 64 + d) * SK + j * 128 + gc * 8, Vs + i * 2048 + t * 8);
    }
    __syncthreads();

    // S = Q K^T : wave computes q-rows w*16..+15 x 128 keys
    floatx4 sacc[8];
#pragma unroll
    for (int n = 0; n < 8; n++)
#pragma unroll
      for (int e = 0; e < 4; e++) sacc[n][e] = 0.f;
#pragma unroll
    for (int kk = 0; kk < 2; kk++) {
      int qrow = w * 16 + l16;
      short8 a = *(const short8*)(Qs + qrow * 64 + (((kk * 4 + quad) ^ (qrow & 7)) * 8));
#pragma unroll
      for (int nc = 0; nc < 8; nc++) {
        int krow = nc * 16 + l16;
        short8 b = *(const short8*)(Ks + krow * 64 + (((kk * 4 + quad) ^ (krow & 7)) * 8));
        sacc[nc] = __builtin_amdgcn_mfma_f32_16x16x32_bf16(a, b, sacc[nc], 0, 0, 0);
      }
    }

    // scale, causal mask (kj <= qi+1 else -10000), + attention_mask
    bool needmask = (j * 128 + 127 > tq * 64 + 1);
    int qbase = tq * 64 + w * 16 + quad * 4;
    float sval[8][4], tmax[4];
#pragma unroll
    for (int r = 0; r < 4; r++) tmax[r] = -1e30f;
#pragma unroll
    for (int nc = 0; nc < 8; nc++) {
      int kg = j * 128 + nc * 16 + l16;
      float amv = (kg >= 1) ? am[bb * SQ + kg - 1] : 0.f;
#pragma unroll
      for (int r = 0; r < 4; r++) {
        float sc = sacc[nc][r] * 0.125f;
        if (needmask && kg > qbase + r + 1) sc = -10000.0f;
        sc += amv;
        sval[nc][r] = sc;
        tmax[r] = fmaxf(tmax[r], sc);
      }
    }
#pragma unroll
    for (int off = 1; off < 16; off <<= 1)
#pragma unroll
      for (int r = 0; r < 4; r++) tmax[r] = fmaxf(tmax[r], __shfl_xor(tmax[r], off));

    float alpha[4];
#pragma unroll
    for (int r = 0; r < 4; r++) {
      float mn = fmaxf(m_i[r], tmax[r]);
      alpha[r] = __expf(m_i[r] - mn);
      m_i[r] = mn;
    }
    float rsum[4] = {0.f, 0.f, 0.f, 0.f};
#pragma unroll
    for (int nc = 0; nc < 8; nc++)
#pragma unroll
      for (int r = 0; r < 4; r++) {
        float p = __expf(sval[nc][r] - m_i[r]);
        sval[nc][r] = p;
        rsum[r] += p;
      }
#pragma unroll
    for (int off = 1; off < 16; off <<= 1)
#pragma unroll
      for (int r = 0; r < 4; r++) rsum[r] += __shfl_xor(rsum[r], off);
#pragma unroll
    for (int r = 0; r < 4; r++) l_i[r] = l_i[r] * alpha[r] + rsum[r];
#pragma unroll
    for (int n = 0; n < 4; n++)
#pragma unroll
      for (int e = 0; e < 4; e++) acc_o[n][e] *= alpha[e];

    // P: C-layout -> wave-private LDS (no barrier needed; in-wave DS ordering)
#pragma unroll
    for (int nc = 0; nc < 8; nc++)
#pragma unroll
      for (int r = 0; r < 4; r++)
        Pw[(quad * 4 + r) * 144 + nc * 16 + l16] = f2bf(sval[nc][r]);

    // O += P V  (Vs holds V^T tile: rows = d, cols = key, swizzled)
#pragma unroll
    for (int kk2 = 0; kk2 < 4; kk2++) {
      short8 a = *(const short8*)(Pw + l16 * 144 + (kk2 * 4 + quad) * 8);
#pragma unroll
      for (int n = 0; n < 4; n++) {
        int vrow = n * 16 + l16;
        short8 b = *(const short8*)(Vs + vrow * 128 + (((kk2 * 4 + quad) ^ (vrow & 7)) * 8));
        acc_o[n] = __builtin_amdgcn_mfma_f32_16x16x32_bf16(a, b, acc_o[n], 0, 0, 0);
      }
    }
  }

  // normalize, repack via LDS, vectorized store
  float inv[4];
#pragma unroll
  for (int r = 0; r < 4; r++) inv[r] = 1.f / l_i[r];
  unsigned short* Os = Ps;   // [64][72]
  __syncthreads();
#pragma unroll
  for (int n = 0; n < 4; n++)
#pragma unroll
    for (int r = 0; r < 4; r++)
      Os[(w * 16 + quad * 4 + r) * 72 + n * 16 + l16] = f2bf(acc_o[n][r] * inv[r]);
  __syncthreads();
#pragma unroll
  for (int i = 0; i < 2; i++) {
    int cid = i * 256 + t, r = cid >> 3, c8 = cid & 7;
    int q = tq * 64 + r;
    if (q < SQ)
      *(short8*)(Ao + (bb * SQ + q) * EMBED + h * HDIM + c8 * 8) =
          *(const short8*)(Os + r * 72 + c8 * 8);
  }
}

// ---------------- launch ----------------
extern "C" void kernel_launch(void* const* d_in, const int* in_sizes, int n_in,
                              void* d_out, int out_size, void* d_ws, size_t ws_size,
                              hipStream_t stream) {
  const float* word   = (const float*)d_in[0];
  const float* img    = (const float*)d_in[1];
  const float* amask  = (const float*)d_in[2];
  const float* attn_w = (const float*)d_in[3];
  const float* attn_b = (const float*)d_in[4];
  const float* proj_w = (const float*)d_in[5];
  const float* proj_b = (const float*)d_in[6];
  const float* ukw    = (const float*)d_in[7];
  const float* ukb    = (const float*)d_in[8];
  const float* uvw    = (const float*)d_in[9];
  const float* uvb    = (const float*)d_in[10];
  float* out = (float*)d_out;

  char* ws = (char*)d_ws;
  unsigned short* Aw     = (unsigned short*)(ws);                 // [0,8MB) A / later Ao
  unsigned short* WtAttn = (unsigned short*)(ws + 8388608);       // [8,14MB)
  unsigned short* WtProj = (unsigned short*)(ws + 14680064);      // [14,16MB) written post-flash
  unsigned short* Vtg    = (unsigned short*)(ws + 8388608);       // [8,16MB) after WtAttn dead
  unsigned short* Qb     = (unsigned short*)(ws + 16777216);      // [16,24MB)
  unsigned short* Kb     = (unsigned short*)(ws + 25165824);      // [24,32MB)
  unsigned short* Vb     = (unsigned short*)(ws + 33554432);      // [32,40MB)
  unsigned short* Ao     = Aw;  // reuse: A dead after QKV GEMM

  k_cast_word<<<2048, 256, 0, stream>>>(word, Aw);
  k_transpose_cast<<<dim3(96, 32), 256, 0, stream>>>(attn_w, WtAttn, 1024, 3072);
  k_img_kv<<<2048, 256, 0, stream>>>(img, ukw, ukb, uvw, uvb, Kb, Vb);
  k_zero_qpad<<<16, 256, 0, stream>>>(Qb);
  k_gemm<0><<<dim3(24, 32), 256, 0, stream>>>(Aw, WtAttn, 1024, attn_b, Qb, Kb, Vb, nullptr);
  k_vt<<<dim3(16, 64), 256, 0, stream>>>(Vb, Vtg);
  k_flash<<<dim3(16, 64), 256, 0, stream>>>(Qb, Kb, Vtg, amask, Ao);
  k_transpose_cast<<<dim3(32, 32), 256, 0, stream>>>(proj_w, WtProj, 1024, 1024);
  k_gemm<1><<<dim3(8, 32), 256, 0, stream>>>(Ao, WtProj, 1024, proj_b, nullptr, nullptr, nullptr, out);
}